// Round 3
// baseline (441.843 us; speedup 1.0000x reference)
//
#include <hip/hip_runtime.h>

// Sparsemax along last axis of (4, 4096, 4096) fp32.
// One block per row; row lives in registers (16 floats/thread).
// tau solves sum(relu(x - tau)) = 1 via Newton from tau0 = max - 1
// (monotone, finite convergence; exit when tau fixed-points, wave-uniform).
// Only elements with x > max-1 can ever be active (tau >= max-1), so they
// are pushed into LDS (~14/row for Gaussian) and ONE wave runs Newton.
// Output stores are nontemporal: output is never re-read, and keeping it
// out of L2/L3 preserves input residency (L3 absorbs ~half the fetches).

constexpr int D = 4096;
constexpr int BLOCK = 256;
constexpr int CHUNKS = D / (BLOCK * 4);   // 4 float4 per thread
constexpr int NEWTON_ITERS = 16;          // hard cap; typically exits ~6
constexpr int CAP = 1024;                 // candidate capacity (4 KB LDS)

typedef float v4f __attribute__((ext_vector_type(4)));

__global__ __launch_bounds__(BLOCK) void sparsemax_kernel(
    const float* __restrict__ in, float* __restrict__ out) {
  __shared__ float smax[4];
  __shared__ float smS[4], smK[4];
  __shared__ float sB;
  __shared__ int scnt;
  __shared__ float cand[CAP];

  const long long row = blockIdx.x;
  const float4* __restrict__ x4 =
      reinterpret_cast<const float4*>(in + row * (long long)D);
  float* __restrict__ yrow = out + row * (long long)D;

  const int t = threadIdx.x;
  const int wave = t >> 6;
  const int lane = t & 63;

  // ---- load row into registers (coalesced float4) ----
  float4 v[CHUNKS];
#pragma unroll
  for (int c = 0; c < CHUNKS; c++) v[c] = x4[t + c * BLOCK];

  // ---- row max (butterfly -> all lanes) ----
  float m = -INFINITY;
#pragma unroll
  for (int c = 0; c < CHUNKS; c++)
    m = fmaxf(m, fmaxf(fmaxf(v[c].x, v[c].y), fmaxf(v[c].z, v[c].w)));
#pragma unroll
  for (int o = 32; o > 0; o >>= 1) m = fmaxf(m, __shfl_xor(m, o));
  if (lane == 0) smax[wave] = m;
  if (t == 0) scnt = 0;
  __syncthreads();
  m = fmaxf(fmaxf(smax[0], smax[1]), fmaxf(smax[2], smax[3]));
  const float thr = m - 1.0f;  // tau0; no x <= thr can ever be active

  // ---- push candidates (x > thr) into LDS (~14/row; atomics are rare) ----
#pragma unroll
  for (int c = 0; c < CHUNKS; c++) {
    float z;
    z = v[c].x; if (z > thr) { int i = atomicAdd(&scnt, 1); if (i < CAP) cand[i] = z; }
    z = v[c].y; if (z > thr) { int i = atomicAdd(&scnt, 1); if (i < CAP) cand[i] = z; }
    z = v[c].z; if (z > thr) { int i = atomicAdd(&scnt, 1); if (i < CAP) cand[i] = z; }
    z = v[c].w; if (z > thr) { int i = atomicAdd(&scnt, 1); if (i < CAP) cand[i] = z; }
  }
  __syncthreads();
  const int n = scnt;

  if (n <= CAP) {
    // ---- Newton on the tiny candidate set, wave 0 only ----
    if (wave == 0) {
      float tau = thr;
      if (n <= 64) {
        // hot path: one candidate per lane, in-register
        const float sentinel = thr - 1.0f;  // never > tau (tau >= thr)
        float z = (lane < n) ? cand[lane] : sentinel;
        for (int it = 0; it < NEWTON_ITERS; it++) {
          float S = 0.0f, K = 0.0f;
          if (z > tau) { S = z; K = 1.0f; }
#pragma unroll
          for (int o = 32; o > 0; o >>= 1) {
            S += __shfl_xor(S, o);
            K += __shfl_xor(K, o);
          }
          float tnew = (S - 1.0f) / K;  // K >= 1: x_max = m > tau always
          if (tnew == tau) break;       // wave-uniform exit
          tau = tnew;
        }
      } else {
        for (int it = 0; it < NEWTON_ITERS; it++) {
          float S = 0.0f, K = 0.0f;
          for (int i = lane; i < n; i += 64) {
            float z = cand[i];
            if (z > tau) { S += z; K += 1.0f; }
          }
#pragma unroll
          for (int o = 32; o > 0; o >>= 1) {
            S += __shfl_xor(S, o);
            K += __shfl_xor(K, o);
          }
          float tnew = (S - 1.0f) / K;
          if (tnew == tau) break;
          tau = tnew;
        }
      }
      if (lane == 0) sB = tau;
    }
  } else {
    // ---- fallback: block-wide Newton over registers (never for Gaussian) ----
    float tau = thr;
    for (int it = 0; it < NEWTON_ITERS; it++) {
      float S = 0.0f, K = 0.0f;
#pragma unroll
      for (int c = 0; c < CHUNKS; c++) {
        float z;
        z = v[c].x; if (z > tau) { S += z; K += 1.0f; }
        z = v[c].y; if (z > tau) { S += z; K += 1.0f; }
        z = v[c].z; if (z > tau) { S += z; K += 1.0f; }
        z = v[c].w; if (z > tau) { S += z; K += 1.0f; }
      }
#pragma unroll
      for (int o = 32; o > 0; o >>= 1) {
        S += __shfl_xor(S, o);
        K += __shfl_xor(K, o);
      }
      if (lane == 0) { smS[wave] = S; smK[wave] = K; }
      __syncthreads();
      float St = smS[0] + smS[1] + smS[2] + smS[3];
      float Kt = smK[0] + smK[1] + smK[2] + smK[3];
      tau = (St - 1.0f) / Kt;
      __syncthreads();
    }
    if (t == 0) sB = tau;
  }
  __syncthreads();
  const float tau = sB;

  // ---- write p = max(x - tau, 0), nontemporal float4 ----
#pragma unroll
  for (int c = 0; c < CHUNKS; c++) {
    v4f o;
    o.x = fmaxf(v[c].x - tau, 0.0f);
    o.y = fmaxf(v[c].y - tau, 0.0f);
    o.z = fmaxf(v[c].z - tau, 0.0f);
    o.w = fmaxf(v[c].w - tau, 0.0f);
    __builtin_nontemporal_store(
        o, reinterpret_cast<v4f*>(yrow) + t + c * BLOCK);
  }
}

extern "C" void kernel_launch(void* const* d_in, const int* in_sizes, int n_in,
                              void* d_out, int out_size, void* d_ws, size_t ws_size,
                              hipStream_t stream) {
  const float* in = (const float*)d_in[0];
  float* out = (float*)d_out;
  const int rows = in_sizes[0] / D;  // 16384
  sparsemax_kernel<<<rows, BLOCK, 0, stream>>>(in, out);
}